// Round 3
// baseline (4332.920 us; speedup 1.0000x reference)
//
#include <hip/hip_runtime.h>

typedef unsigned short u16;
typedef unsigned int   u32;
typedef __attribute__((ext_vector_type(8))) short  short8;
typedef __attribute__((ext_vector_type(4))) float  floatx4;

#define DEV __device__ __forceinline__

DEV float bf2f(u16 u){ return __uint_as_float(((u32)u) << 16); }
DEV u16 f2bf(float x){
  u32 u = __float_as_uint(x);
  u += 0x7FFFu + ((u >> 16) & 1u);
  return (u16)(u >> 16);
}
DEV float blo(u32 u){ return __uint_as_float(u << 16); }
DEV float bhi(u32 u){ return __uint_as_float(u & 0xffff0000u); }

DEV void async16(const void* g, void* l){
  __builtin_amdgcn_global_load_lds((__attribute__((address_space(1))) void*)g,
                                   (__attribute__((address_space(3))) void*)l,
                                   16, 0, 0);
}

// ---------------- problem constants --------------------------------------
constexpr int NN   = 100000;   // total blocks
constexpr int FF   = 1000;     // files
constexpr int KPF  = 100;      // blocks per file
constexpr int DH   = 512;

// output offsets (floats)
constexpr size_t OUT_HBLK  = 0;
constexpr size_t OUT_ALPHA = 51200000;
constexpr size_t OUT_HFILE = 51300000;
constexpr size_t OUT_ZSH   = 51812000;
constexpr size_t OUT_ZPR   = 52068000;
constexpr size_t OUT_LOG   = 52324000;
constexpr size_t OUT_BUG   = 52424000;
constexpr size_t OUT_LOSS  = 52425000;

// workspace offsets (bytes).
constexpr size_t WS_A      = 0;
constexpr size_t WS_M1     = 0;
constexpr size_t WS_H1     = 102400000;
constexpr size_t WS_HBLK   = 0;
constexpr size_t WS_H0     = 204800000;
constexpr size_t WS_M2     = 204800000;
constexpr size_t WS_SCOREP = 307200000;  // 2 * N * 4 B used
constexpr size_t WS_WT     = 308800000;  // 1729536 bf16 elems
constexpr size_t WS_HFILEB = 312300000;  // 1000*512 bf16
constexpr size_t WS_TSH    = 313400000;  // 1000*256 bf16
constexpr size_t WS_TPR    = 314000000;
constexpr size_t WS_ZPRB   = 314600000;
constexpr size_t WS_ORTHOP = 315200000;  // 256 floats

// weight-table element offsets inside WS_WT (bf16 elements)
constexpr int WT_FUS = 0;        // [512][1024]
constexpr int WT_G1  = 524288;   // [512][512]
constexpr int WT_G2  = 786432;
constexpr int WT_ATT = 1048576;
constexpr int WT_SH1 = 1310720;  // [256][512]
constexpr int WT_SH2 = 1441792;  // [256][256]
constexpr int WT_PR1 = 1507328;  // [256][512]
constexpr int WT_PR2 = 1638400;  // [256][256]
constexpr int WT_DPR = 1703936;  // [100][256]
constexpr int WT_TOT = 1729536;

// ---------------- prep: transpose + convert all weights to bf16 B^T -------
struct PrepTab {
  const float* src[9];
  int K[9];
  int N[9];
  int prefix[10];
};

__global__ __launch_bounds__(256) void prep_w(PrepTab t, u16* __restrict__ dst){
  int gid = blockIdx.x * 256 + threadIdx.x;
  if (gid >= t.prefix[9]) return;
  int i = 0;
  while (gid >= t.prefix[i+1]) ++i;
  int e  = gid - t.prefix[i];
  int Ni = t.N[i];
  int k  = e / Ni;
  int n  = e - k * Ni;
  dst[t.prefix[i] + (size_t)n * t.K[i] + k] = f2bf(t.src[i][(size_t)k * Ni + n]);
}

// ---------------- build A = [h_sem | e_struct] bf16 [N,1024] --------------
__global__ __launch_bounds__(256) void build_A(const float* __restrict__ hsem,
                                               const float* __restrict__ est,
                                               u16* __restrict__ out){
  int gid = blockIdx.x * 256 + threadIdx.x;   // one thread per 8 cols
  int row = gid >> 7;
  int c   = (gid & 127) << 3;
  const float* src = (c < 768) ? (hsem + (size_t)row * 768 + c)
                               : (est  + (size_t)row * 256 + (c - 768));
  float4 v0 = *(const float4*)src;
  float4 v1 = *(const float4*)(src + 4);
  uint4 o;
  o.x = (u32)f2bf(v0.x) | ((u32)f2bf(v0.y) << 16);
  o.y = (u32)f2bf(v0.z) | ((u32)f2bf(v0.w) << 16);
  o.z = (u32)f2bf(v1.x) | ((u32)f2bf(v1.y) << 16);
  o.w = (u32)f2bf(v1.z) | ((u32)f2bf(v1.w) << 16);
  *(uint4*)(out + (size_t)row * 1024 + c) = o;
}

// ============ 256x256 / 8-wave / BK=32 MFMA GEMM (big shapes) =============
// C[M,N] = A[M,K]bf16 * B^T[N,K]bf16.  512 threads (2x4 waves, 128x64/wave).
// v3 changes vs v2 (both-low-util diagnosis = structural stall at 1 blk/CU):
//  * BK=32 double-buffer -> 64 KB static LDS + 4 KB scratch = 68 KB
//    => 2 blocks/CU resident; block pairs share the A-panel (ty adjacent via
//    XCD swizzle) and hide each other's barrier/vmcnt stalls (m230: 2-phase
//    schedules need TLP).
//  * counted vmcnt(4), never 0 mid-loop; prefetch depth 2 K-tiles.
//  * k-slot involution swizzle: LDS(r,s) holds chunk s^((r>>1)&3); read slot
//    lq^((lr>>1)&3); global source pre-swizzled (both-sides rule).
//  * operand-swapped MFMA: mfma(bf, af) => lane owns 4 CONSECUTIVE cols
//    (gc = wcol+ni*16+lq*4+r2, gr = wrow+mi*16+lr): float4 bias loads and
//    packed 8-B uint2 stores (32/lane) instead of 128 scalar u16 stores.
//  * MODE 3 row-sum: shfl_xor(16,32) across lq + explicit cross-wave LDS
//    reduction (correct by construction, no same-slot write ordering).
// MODE 0: store bf16 | 3: tanh*ctx row-reduce score partial (per N-tile).
template<int MODE, bool BIAS>
__global__ __launch_bounds__(512, 4) void gemm256(
    const u16* __restrict__ A, const u16* __restrict__ B,
    int M, int N, int K,
    const float* __restrict__ bias,
    u16* __restrict__ outb,
    const float* __restrict__ ctx, float* __restrict__ scorep)
{
  __shared__ u16 S[2 * 16384];        // [buf][A|B][256][32] u16 = 64 KB
  __shared__ float red[8 * 128];      // MODE3 cross-wave reduce scratch
  const int tid  = threadIdx.x;
  const int wid  = tid >> 6, lane = tid & 63;
  const int lq   = lane >> 4, lr = lane & 15;

  // XCD-bijective chunked swizzle + N-fastest tile decode
  const int ny  = N >> 8;
  const int nwg = (int)gridDim.x;
  const int q   = nwg >> 3, r = nwg & 7;
  const int xcd = (int)blockIdx.x & 7, pos = (int)blockIdx.x >> 3;
  const int lid = (xcd < r ? xcd * (q + 1) : r * (q + 1) + (xcd - r) * q) + pos;
  const int ty  = lid % ny, tx = lid / ny;
  const int m0  = tx << 8, n0 = ty << 8;

  const int wr = wid >> 2, wc = wid & 3;      // 2 x 4 wave grid
  const int wrow = wr << 7, wcol = wc << 6;   // 128 x 64 per-wave tile

  // staging: wave covers 32 rows (2 instrs x 16 rows).  Lane L writes LDS
  // row base+(L>>2), slot L&3; global k-chunk fetched = (L&3)^((L>>3)&3)
  // so LDS(r,s) holds chunk s^((r>>1)&3)  [involution, r low bits = L>>2].
  const int g = (((lane & 3) ^ ((lane >> 3) & 3)) << 3);
  int ra0 = m0 + (wid << 5) + (lane >> 2);
  int ra1 = min(ra0 + 16, M - 1);
  ra0 = min(ra0, M - 1);
  const int rb0 = n0 + (wid << 5) + (lane >> 2);   // N exact multiple, no clamp
  const u16* pa0 = A + (size_t)ra0 * K + g;
  const u16* pa1 = A + (size_t)ra1 * K + g;
  const u16* pb0 = B + (size_t)rb0 * K + g;
  const u16* pb1 = B + (size_t)(rb0 + 16) * K + g;

  auto STAGE = [&](int p){
    u16* ab = S + (p << 14) + (wid << 10);   // buf p, A region, wave rows
    u16* bb = ab + 8192;                     // B region
    async16(pa0, ab); async16(pa1, ab + 512);
    async16(pb0, bb); async16(pb1, bb + 512);
    pa0 += 32; pa1 += 32; pb0 += 32; pb1 += 32;
  };

  floatx4 acc[8][4];
  #pragma unroll
  for (int i = 0; i < 8; ++i)
    #pragma unroll
    for (int j = 0; j < 4; ++j)
      acc[i][j] = floatx4{0.f, 0.f, 0.f, 0.f};

  const int NT = K >> 5;            // BK = 32
  STAGE(0);
  STAGE(1);

  const int rs = (lr >> 1) & 3;     // read-side row bits
  for (int kt = 0; kt < NT; ++kt) {
    // own oldest 4 staging loads (tile kt) must have landed; rest in flight
    if (kt + 1 < NT) asm volatile("s_waitcnt vmcnt(4)" ::: "memory");
    else             asm volatile("s_waitcnt vmcnt(0)" ::: "memory");
    __builtin_amdgcn_s_barrier();
    __builtin_amdgcn_sched_barrier(0);
    const u16* ap = S + ((kt & 1) << 14);
    const u16* bp = ap + 8192;
    short8 af[8], bf[4];
    const int sl = (lq ^ rs) << 3;
    #pragma unroll
    for (int mi = 0; mi < 8; ++mi)   // A row = wrow+mi*16+lr, k-chunk lq
      af[mi] = *(const short8*)(ap + ((wrow + mi * 16 + lr) << 5) + sl);
    #pragma unroll
    for (int ni = 0; ni < 4; ++ni)   // B col = wcol+ni*16+lr, k-chunk lq
      bf[ni] = *(const short8*)(bp + ((wcol + ni * 16 + lr) << 5) + sl);
    __builtin_amdgcn_s_setprio(1);
    #pragma unroll
    for (int mi = 0; mi < 8; ++mi)
      #pragma unroll
      for (int ni = 0; ni < 4; ++ni)   // swapped: D[n -> lq*4+r2][m -> lr]
        acc[mi][ni] = __builtin_amdgcn_mfma_f32_16x16x32_bf16(bf[ni], af[mi], acc[mi][ni], 0, 0, 0);
    __builtin_amdgcn_s_setprio(0);
    __builtin_amdgcn_s_barrier();
    __builtin_amdgcn_sched_barrier(0);
    if (kt + 2 < NT) STAGE(kt & 1);   // kt+2 has same parity -> same buf
  }

  // swapped C layout: acc[mi][ni][r2] = C[wrow+mi*16+lr][wcol+ni*16+lq*4+r2]
  if constexpr (MODE == 3) {
    float bvv[16], cvv[16];
    #pragma unroll
    for (int ni = 0; ni < 4; ++ni) {
      int gc0 = n0 + wcol + ni * 16 + (lq << 2);
      float4 b4 = *(const float4*)(bias + gc0);
      float4 c4 = *(const float4*)(ctx + gc0);
      bvv[ni*4+0] = b4.x; bvv[ni*4+1] = b4.y; bvv[ni*4+2] = b4.z; bvv[ni*4+3] = b4.w;
      cvv[ni*4+0] = c4.x; cvv[ni*4+1] = c4.y; cvv[ni*4+2] = c4.z; cvv[ni*4+3] = c4.w;
    }
    #pragma unroll
    for (int mi = 0; mi < 8; ++mi) {
      float p = 0.f;
      #pragma unroll
      for (int ni = 0; ni < 4; ++ni)
        #pragma unroll
        for (int r2 = 0; r2 < 4; ++r2)
          p += tanhf(acc[mi][ni][r2] + bvv[ni*4+r2]) * cvv[ni*4+r2];
      p += __shfl_xor(p, 16);          // reduce across lq (same row lr)
      p += __shfl_xor(p, 32);
      if (lq == 0) red[wid * 128 + mi * 16 + lr] = p;   // wave's 64-col sum
    }
    __syncthreads();
    if (wc == 0) {                     // waves 0,4 combine their row-strip
      #pragma unroll
      for (int h = 0; h < 2; ++h) {
        int rr = lane + h * 64;        // row within 128-row strip
        int base = (wr << 2) * 128 + rr;
        float s4 = red[base] + red[base + 128] + red[base + 256] + red[base + 384];
        int gr = m0 + (wr << 7) + rr;
        if (gr < M) scorep[(size_t)ty * M + gr] = s4;
      }
    }
  } else {
    float4 bv[4];
    #pragma unroll
    for (int ni = 0; ni < 4; ++ni) {
      if (BIAS) bv[ni] = *(const float4*)(bias + n0 + wcol + ni * 16 + (lq << 2));
      else      bv[ni] = make_float4(0.f, 0.f, 0.f, 0.f);
    }
    #pragma unroll
    for (int mi = 0; mi < 8; ++mi) {
      int gr = m0 + wrow + mi * 16 + lr;
      if (gr >= M) continue;
      u16* rp = outb + (size_t)gr * N;
      #pragma unroll
      for (int ni = 0; ni < 4; ++ni) {
        float v0 = acc[mi][ni][0] + bv[ni].x;
        float v1 = acc[mi][ni][1] + bv[ni].y;
        float v2 = acc[mi][ni][2] + bv[ni].z;
        float v3 = acc[mi][ni][3] + bv[ni].w;
        uint2 st;
        st.x = (u32)f2bf(v0) | ((u32)f2bf(v1) << 16);
        st.y = (u32)f2bf(v2) | ((u32)f2bf(v3) << 16);
        *(uint2*)(rp + n0 + wcol + ni * 16 + (lq << 2)) = st;
      }
    }
  }
}

// ---------------- MFMA GEMM 128x128 (small head shapes) -------------------
// MODE 0: store bf16 | 1: store f32 | 2: both | 3: tanh*ctx row-reduce score
template<int MODE, bool BIAS, bool RELU>
__global__ __launch_bounds__(256) void gemm_bt(
    const u16* __restrict__ A, const u16* __restrict__ B,
    int M, int N, int K, int ny,
    const float* __restrict__ bias,
    u16* __restrict__ outb, float* __restrict__ outf,
    int ldc, int nvalid,
    const float* __restrict__ ctx, float* __restrict__ scorep)
{
  __shared__ u16 As[3 * 4096];
  __shared__ u16 Bs[3 * 4096];
  const int tid  = threadIdx.x;
  const int wave = tid >> 6, lane = tid & 63;

  const int nwg = (int)gridDim.x;
  const int q   = nwg >> 3, r = nwg & 7;
  const int xcd = (int)blockIdx.x & 7, pos = (int)blockIdx.x >> 3;
  const int lid = (xcd < r ? xcd * (q + 1) : r * (q + 1) + (xcd - r) * q) + pos;
  const int ty  = lid % ny, tx = lid / ny;
  const int m0  = tx << 7, n0 = ty << 7;

  const int wm = (wave & 1) << 6, wn = (wave >> 1) << 6;
  const int lq = lane >> 4, lr = lane & 15;

  floatx4 acc[4][4];
  #pragma unroll
  for (int i = 0; i < 4; ++i)
    #pragma unroll
    for (int j = 0; j < 4; ++j)
      acc[i][j] = floatx4{0.f, 0.f, 0.f, 0.f};

  int arow = m0 + (wave << 4) + (lane >> 2);
  int ar0 = min(arow, M - 1);
  int ar1 = min(arow + 64, M - 1);
  int brow = n0 + (wave << 4) + (lane >> 2);
  int br0 = min(brow, N - 1);
  int br1 = min(brow + 64, N - 1);
  const int kc = (((lane & 3) ^ ((lane >> 3) & 3)) << 3);
  const u16* ga0 = A + (size_t)ar0 * K + kc;
  const u16* ga1 = A + (size_t)ar1 * K + kc;
  const u16* gb0 = B + (size_t)br0 * K + kc;
  const u16* gb1 = B + (size_t)br1 * K + kc;

  auto STAGE = [&](int buf){
    u16* as = As + (buf << 12);
    u16* bs = Bs + (buf << 12);
    async16(ga0, as + (wave << 9));
    async16(ga1, as + 2048 + (wave << 9));
    async16(gb0, bs + (wave << 9));
    async16(gb1, bs + 2048 + (wave << 9));
    ga0 += 32; ga1 += 32; gb0 += 32; gb1 += 32;
  };

  const int nIt = K >> 5;
  STAGE(0);
  if (nIt > 1) STAGE(1);
  const int rsw = (lr >> 1) & 3;
  int bt = 0;
  for (int it = 0; it < nIt; ++it) {
    if (it + 1 < nIt) asm volatile("s_waitcnt vmcnt(4) lgkmcnt(0)" ::: "memory");
    else              asm volatile("s_waitcnt vmcnt(0) lgkmcnt(0)" ::: "memory");
    __builtin_amdgcn_s_barrier();
    __builtin_amdgcn_sched_barrier(0);
    if (it + 2 < nIt) { int b2 = bt + 2; if (b2 >= 3) b2 -= 3; STAGE(b2); }
    const u16* as = As + (bt << 12);
    const u16* bs = Bs + (bt << 12);
    short8 af[4], bfr[4];
    #pragma unroll
    for (int mi = 0; mi < 4; ++mi)
      af[mi] = *(const short8*)(as + ((wm + mi * 16 + lr) << 5) + ((lq ^ rsw) << 3));
    #pragma unroll
    for (int ni = 0; ni < 4; ++ni)
      bfr[ni] = *(const short8*)(bs + ((wn + ni * 16 + lr) << 5) + ((lq ^ rsw) << 3));
    #pragma unroll
    for (int mi = 0; mi < 4; ++mi)
      #pragma unroll
      for (int ni = 0; ni < 4; ++ni)
        acc[mi][ni] = __builtin_amdgcn_mfma_f32_16x16x32_bf16(af[mi], bfr[ni], acc[mi][ni], 0, 0, 0);
    if (++bt == 3) bt = 0;
  }

  if constexpr (MODE == 3) {
    #pragma unroll
    for (int mi = 0; mi < 4; ++mi) {
      #pragma unroll
      for (int r2 = 0; r2 < 4; ++r2) {
        float p = 0.f;
        #pragma unroll
        for (int ni = 0; ni < 4; ++ni) {
          int gc = n0 + wn + ni * 16 + lr;
          p += tanhf(acc[mi][ni][r2] + bias[gc]) * ctx[gc];
        }
        p += __shfl_xor(p, 1); p += __shfl_xor(p, 2);
        p += __shfl_xor(p, 4); p += __shfl_xor(p, 8);
        int gr = m0 + wm + mi * 16 + lq * 4 + r2;
        if (lr == 0 && gr < M) scorep[(size_t)ty * M + gr] = p;
      }
    }
  } else {
    #pragma unroll
    for (int mi = 0; mi < 4; ++mi) {
      int grb = m0 + wm + mi * 16 + lq * 4;
      #pragma unroll
      for (int ni = 0; ni < 4; ++ni) {
        int gc = n0 + wn + ni * 16 + lr;
        if (gc >= nvalid) continue;
        float bv = BIAS ? bias[gc] : 0.f;
        #pragma unroll
        for (int r2 = 0; r2 < 4; ++r2) {
          int gr = grb + r2;
          if (gr >= M) continue;
          float v = acc[mi][ni][r2] + bv;
          if (RELU) v = fmaxf(v, 0.f);
          if (MODE == 0 || MODE == 2) outb[(size_t)gr * ldc + gc] = f2bf(v);
          if (MODE == 1 || MODE == 2) outf[(size_t)gr * ldc + gc] = v;
        }
      }
    }
  }
}

// ---------------- GCN aggregation: 5-tap stencil along position ----------
DEV float dinv_of(int p){
  return rsqrtf((float)(1 + min(p, 2) + min(99 - p, 2)));
}

template<bool RELU, bool DUAL>
__global__ __launch_bounds__(256) void agg_k(const u16* __restrict__ m,
                                             const float* __restrict__ bias,
                                             u16* __restrict__ outb,
                                             float* __restrict__ outf){
  int gid = blockIdx.x * 256 + threadIdx.x;   // 64 threads per row (8 cols ea)
  int row = gid >> 6;
  int c   = (gid & 63) << 3;
  int pos = row % KPF;
  float ds = dinv_of(pos);
  float a0=0,a1=0,a2=0,a3=0,a4=0,a5=0,a6=0,a7=0;
  #pragma unroll
  for (int d = -2; d <= 2; ++d) {
    int p2 = pos + d;
    if (p2 < 0 || p2 >= KPF) continue;
    float w = ds * dinv_of(p2);
    uint4 v = *(const uint4*)(m + (size_t)(row + d) * DH + c);
    a0 += w * blo(v.x); a1 += w * bhi(v.x);
    a2 += w * blo(v.y); a3 += w * bhi(v.y);
    a4 += w * blo(v.z); a5 += w * bhi(v.z);
    a6 += w * blo(v.w); a7 += w * bhi(v.w);
  }
  float o[8] = {a0,a1,a2,a3,a4,a5,a6,a7};
  #pragma unroll
  for (int j = 0; j < 8; ++j) {
    o[j] += bias[c + j];
    if (RELU) o[j] = fmaxf(o[j], 0.f);
  }
  uint4 st;
  st.x = (u32)f2bf(o[0]) | ((u32)f2bf(o[1]) << 16);
  st.y = (u32)f2bf(o[2]) | ((u32)f2bf(o[3]) << 16);
  st.z = (u32)f2bf(o[4]) | ((u32)f2bf(o[5]) << 16);
  st.w = (u32)f2bf(o[6]) | ((u32)f2bf(o[7]) << 16);
  *(uint4*)(outb + (size_t)row * DH + c) = st;
  if (DUAL) {
    float4 f0 = {o[0], o[1], o[2], o[3]};
    float4 f1 = {o[4], o[5], o[6], o[7]};
    *(float4*)(outf + (size_t)row * DH + c)     = f0;
    *(float4*)(outf + (size_t)row * DH + c + 4) = f1;
  }
}

// ---------------- per-file softmax + attention pooling --------------------
__global__ __launch_bounds__(256) void pool_k(const float* __restrict__ sp,
                                              const u16* __restrict__ hblk,
                                              float* __restrict__ alpha_out,
                                              float* __restrict__ hfile_f,
                                              u16* __restrict__ hfile_b){
  int f = blockIdx.x, tid = threadIdx.x;
  __shared__ float sAl[KPF];
  __shared__ float red[8];
  float s = -INFINITY;
  if (tid < KPF) {
    int r = f * KPF + tid;
    s = sp[r] + sp[NN + r];          // 2 N-tile partials (256-wide each)
  }
  float mx = s;
  for (int off = 32; off >= 1; off >>= 1) mx = fmaxf(mx, __shfl_xor(mx, off));
  if ((tid & 63) == 0) red[tid >> 6] = mx;
  __syncthreads();
  mx = fmaxf(fmaxf(red[0], red[1]), fmaxf(red[2], red[3]));
  float ex = (tid < KPF) ? expf(s - mx) : 0.f;
  float sm = ex;
  for (int off = 32; off >= 1; off >>= 1) sm += __shfl_xor(sm, off);
  if ((tid & 63) == 0) red[4 + (tid >> 6)] = sm;
  __syncthreads();
  sm = red[4] + red[5] + red[6] + red[7];
  float al = ex / sm;
  if (tid < KPF) { alpha_out[(size_t)f * KPF + tid] = al; sAl[tid] = al; }
  __syncthreads();
  const u16* base = hblk + (size_t)f * KPF * DH;
  float acc0 = 0.f, acc1 = 0.f;
  for (int i = 0; i < KPF; ++i) {
    float w = sAl[i];
    acc0 += w * bf2f(base[i * DH + tid]);
    acc1 += w * bf2f(base[i * DH + 256 + tid]);
  }
  hfile_f[(size_t)f * DH + tid]       = acc0;
  hfile_f[(size_t)f * DH + 256 + tid] = acc1;
  hfile_b[(size_t)f * DH + tid]       = f2bf(acc0);
  hfile_b[(size_t)f * DH + 256 + tid] = f2bf(acc1);
}

// ---------------- bug logit: h_file @ W_bug + b ---------------------------
__global__ __launch_bounds__(256) void bug_k(const float* __restrict__ hfile,
                                             const float* __restrict__ w,
                                             const float* __restrict__ b,
                                             float* __restrict__ out){
  int row  = blockIdx.x * 4 + (threadIdx.x >> 6);
  int lane = threadIdx.x & 63;
  const float* h = hfile + (size_t)row * DH;
  float s = 0.f;
  #pragma unroll
  for (int j = 0; j < 8; ++j) s += h[lane + j * 64] * w[lane + j * 64];
  for (int off = 32; off >= 1; off >>= 1) s += __shfl_xor(s, off);
  if (lane == 0) out[row] = s + b[0];
}

// ---------------- ortho loss: mean((z_sh^T z_pr)^2) -----------------------
__global__ __launch_bounds__(256) void ortho_k(const float* __restrict__ zsh,
                                               const float* __restrict__ zpr,
                                               float* __restrict__ part){
  int bi = blockIdx.x >> 4, bj = blockIdx.x & 15;
  int ty = threadIdx.x >> 4, tx = threadIdx.x & 15;
  __shared__ float sa[64 * 16], sb[64 * 16];
  float acc = 0.f;
  for (int k0 = 0; k0 < FF; k0 += 64) {
    #pragma unroll
    for (int q = 0; q < 4; ++q) {
      int kk = ty + q * 16;
      int k  = k0 + kk;
      float va = 0.f, vb = 0.f;
      if (k < FF) {
        va = zsh[(size_t)k * 256 + bi * 16 + tx];
        vb = zpr[(size_t)k * 256 + bj * 16 + tx];
      }
      sa[kk * 16 + tx] = va;
      sb[kk * 16 + tx] = vb;
    }
    __syncthreads();
    #pragma unroll 8
    for (int kk = 0; kk < 64; ++kk) acc += sa[kk * 16 + ty] * sb[kk * 16 + tx];
    __syncthreads();
  }
  float ssq = acc * acc;
  for (int off = 32; off >= 1; off >>= 1) ssq += __shfl_xor(ssq, off);
  __shared__ float r[4];
  if ((threadIdx.x & 63) == 0) r[threadIdx.x >> 6] = ssq;
  __syncthreads();
  if (threadIdx.x == 0) part[blockIdx.x] = r[0] + r[1] + r[2] + r[3];
}

__global__ __launch_bounds__(256) void ortho_fin(const float* __restrict__ part,
                                                 float* __restrict__ out){
  int tid = threadIdx.x;
  float s = part[tid];
  for (int off = 32; off >= 1; off >>= 1) s += __shfl_xor(s, off);
  __shared__ float r[4];
  if ((tid & 63) == 0) r[tid >> 6] = s;
  __syncthreads();
  if (tid == 0) out[0] = (r[0] + r[1] + r[2] + r[3]) * (1.0f / 65536.0f);
}

// ==========================================================================
extern "C" void kernel_launch(void* const* d_in, const int* in_sizes, int n_in,
                              void* d_out, int out_size, void* d_ws, size_t ws_size,
                              hipStream_t stream) {
  const float* h_sem    = (const float*)d_in[0];
  const float* e_struct = (const float*)d_in[1];
  const float* W_fusion = (const float*)d_in[2];
  const float* b_fusion = (const float*)d_in[3];
  const float* W_g1     = (const float*)d_in[4];
  const float* b_g1     = (const float*)d_in[5];
  const float* W_g2     = (const float*)d_in[6];
  const float* b_g2     = (const float*)d_in[7];
  const float* W_att    = (const float*)d_in[8];
  const float* b_att    = (const float*)d_in[9];
  const float* context  = (const float*)d_in[10];
  const float* W_sh1    = (const float*)d_in[11];
  const float* b_sh1    = (const float*)d_in[12];
  const float* W_sh2    = (const float*)d_in[13];
  const float* b_sh2    = (const float*)d_in[14];
  const float* W_pr1    = (const float*)d_in[15];
  const float* b_pr1    = (const float*)d_in[16];
  const float* W_pr2    = (const float*)d_in[17];
  const float* b_pr2    = (const float*)d_in[18];
  const float* W_dpr    = (const float*)d_in[19];
  const float* b_dpr    = (const float*)d_in[20];
  const float* W_bug    = (const float*)d_in[21];
  const float* b_bug    = (const float*)d_in[22];

  char*  ws  = (char*)d_ws;
  float* out = (float*)d_out;

  u16*   Abf    = (u16*)(ws + WS_A);
  u16*   h0b    = (u16*)(ws + WS_H0);
  u16*   m1b    = (u16*)(ws + WS_M1);
  u16*   h1b    = (u16*)(ws + WS_H1);
  u16*   m2b    = (u16*)(ws + WS_M2);
  u16*   hblkb  = (u16*)(ws + WS_HBLK);
  float* scorep = (float*)(ws + WS_SCOREP);
  u16*   WT     = (u16*)(ws + WS_WT);
  u16*   hfileb = (u16*)(ws + WS_HFILEB);
  u16*   tshb   = (u16*)(ws + WS_TSH);
  u16*   tprb   = (u16*)(ws + WS_TPR);
  u16*   zprb   = (u16*)(ws + WS_ZPRB);
  float* opart  = (float*)(ws + WS_ORTHOP);

  // 1. weights -> bf16 B^T
  PrepTab t;
  const float* srcs[9] = {W_fusion, W_g1, W_g2, W_att, W_sh1, W_sh2, W_pr1, W_pr2, W_dpr};
  int Ks[9] = {1024, 512, 512, 512, 512, 256, 512, 256, 256};
  int Ns[9] = {512, 512, 512, 512, 256, 256, 256, 256, 100};
  int pre[10] = {WT_FUS, WT_G1, WT_G2, WT_ATT, WT_SH1, WT_SH2, WT_PR1, WT_PR2, WT_DPR, WT_TOT};
  for (int i = 0; i < 9; ++i) { t.src[i] = srcs[i]; t.K[i] = Ks[i]; t.N[i] = Ns[i]; }
  for (int i = 0; i < 10; ++i) t.prefix[i] = pre[i];
  prep_w<<<(WT_TOT + 255) / 256, 256, 0, stream>>>(t, WT);

  // 2. A = [h_sem | e_struct] bf16
  build_A<<<NN * 128 / 256, 256, 0, stream>>>(h_sem, e_struct, Abf);

  // 3. h0 = A @ W_fusion + b  (bf16)  [391 M-tiles x 2 N-tiles]
  gemm256<0, true><<<391 * 2, 512, 0, stream>>>(
      Abf, WT + WT_FUS, NN, 512, 1024, b_fusion, h0b, nullptr, nullptr);

  // 4. m1 = h0 @ W_g1
  gemm256<0, false><<<391 * 2, 512, 0, stream>>>(
      h0b, WT + WT_G1, NN, 512, 512, nullptr, m1b, nullptr, nullptr);

  // 5. h1 = relu(agg(m1) + b_g1)
  agg_k<true, false><<<NN * 64 / 256, 256, 0, stream>>>(m1b, b_g1, h1b, nullptr);

  // 6. m2 = h1 @ W_g2
  gemm256<0, false><<<391 * 2, 512, 0, stream>>>(
      h1b, WT + WT_G2, NN, 512, 512, nullptr, m2b, nullptr, nullptr);

  // 7. h_blk = agg(m2) + b_g2   (fp32 -> d_out, bf16 -> ws)
  agg_k<false, true><<<NN * 64 / 256, 256, 0, stream>>>(m2b, b_g2, hblkb, out + OUT_HBLK);

  // 8. score partials = rowsum(tanh(h_blk@W_att + b_att) * context)
  gemm256<3, true><<<391 * 2, 512, 0, stream>>>(
      hblkb, WT + WT_ATT, NN, 512, 512, b_att, nullptr, context, scorep);

  // 9. per-file softmax + pooling
  pool_k<<<FF, 256, 0, stream>>>(scorep, hblkb, out + OUT_ALPHA, out + OUT_HFILE, hfileb);

  // 10. heads (128^2 kernel; shapes too small for 256^2)
  gemm_bt<0, true, true><<<8 * 2, 256, 0, stream>>>(
      hfileb, WT + WT_SH1, FF, 256, 512, 2, b_sh1, tshb, nullptr, 256, 256, nullptr, nullptr);
  gemm_bt<1, true, false><<<8 * 2, 256, 0, stream>>>(
      tshb, WT + WT_SH2, FF, 256, 256, 2, b_sh2, nullptr, out + OUT_ZSH, 256, 256, nullptr, nullptr);
  gemm_bt<0, true, true><<<8 * 2, 256, 0, stream>>>(
      hfileb, WT + WT_PR1, FF, 256, 512, 2, b_pr1, tprb, nullptr, 256, 256, nullptr, nullptr);
  gemm_bt<2, true, false><<<8 * 2, 256, 0, stream>>>(
      tprb, WT + WT_PR2, FF, 256, 256, 2, b_pr2, zprb, out + OUT_ZPR, 256, 256, nullptr, nullptr);
  gemm_bt<1, true, false><<<8 * 1, 256, 0, stream>>>(
      zprb, WT + WT_DPR, FF, 100, 256, 1, b_dpr, nullptr, out + OUT_LOG, 100, 100, nullptr, nullptr);

  // 11. bug logit
  bug_k<<<FF / 4, 256, 0, stream>>>(out + OUT_HFILE, W_bug, b_bug, out + OUT_BUG);

  // 12. ortho loss
  ortho_k<<<256, 256, 0, stream>>>(out + OUT_ZSH, out + OUT_ZPR, opart);
  ortho_fin<<<1, 256, 0, stream>>>(opart, out + OUT_LOSS);
}

// Round 4
// 1336.869 us; speedup vs baseline: 3.2411x; 3.2411x over previous
//
#include <hip/hip_runtime.h>

typedef unsigned short u16;
typedef unsigned int   u32;
typedef __attribute__((ext_vector_type(8))) short  short8;
typedef __attribute__((ext_vector_type(4))) float  floatx4;

#define DEV __device__ __forceinline__

DEV float bf2f(u16 u){ return __uint_as_float(((u32)u) << 16); }
DEV u16 f2bf(float x){
  u32 u = __float_as_uint(x);
  u += 0x7FFFu + ((u >> 16) & 1u);
  return (u16)(u >> 16);
}
DEV float blo(u32 u){ return __uint_as_float(u << 16); }
DEV float bhi(u32 u){ return __uint_as_float(u & 0xffff0000u); }

DEV void async16(const void* g, void* l){
  __builtin_amdgcn_global_load_lds((__attribute__((address_space(1))) void*)g,
                                   (__attribute__((address_space(3))) void*)l,
                                   16, 0, 0);
}

// ---------------- problem constants --------------------------------------
constexpr int NN   = 100000;   // total blocks
constexpr int FF   = 1000;     // files
constexpr int KPF  = 100;      // blocks per file
constexpr int DH   = 512;

// output offsets (floats)
constexpr size_t OUT_HBLK  = 0;
constexpr size_t OUT_ALPHA = 51200000;
constexpr size_t OUT_HFILE = 51300000;
constexpr size_t OUT_ZSH   = 51812000;
constexpr size_t OUT_ZPR   = 52068000;
constexpr size_t OUT_LOG   = 52324000;
constexpr size_t OUT_BUG   = 52424000;
constexpr size_t OUT_LOSS  = 52425000;

// workspace offsets (bytes).
constexpr size_t WS_A      = 0;
constexpr size_t WS_M1     = 0;
constexpr size_t WS_H1     = 102400000;
constexpr size_t WS_HBLK   = 0;
constexpr size_t WS_H0     = 204800000;
constexpr size_t WS_M2     = 204800000;
constexpr size_t WS_SCOREP = 307200000;  // 2 * N * 4 B used
constexpr size_t WS_WT     = 308800000;  // 1729536 bf16 elems
constexpr size_t WS_HFILEB = 312300000;  // 1000*512 bf16
constexpr size_t WS_TSH    = 313400000;  // 1000*256 bf16
constexpr size_t WS_TPR    = 314000000;
constexpr size_t WS_ZPRB   = 314600000;
constexpr size_t WS_ORTHOP = 315200000;  // 256 floats

// weight-table element offsets inside WS_WT (bf16 elements)
constexpr int WT_FUS = 0;        // [512][1024]
constexpr int WT_G1  = 524288;   // [512][512]
constexpr int WT_G2  = 786432;
constexpr int WT_ATT = 1048576;
constexpr int WT_SH1 = 1310720;  // [256][512]
constexpr int WT_SH2 = 1441792;  // [256][256]
constexpr int WT_PR1 = 1507328;  // [256][512]
constexpr int WT_PR2 = 1638400;  // [256][256]
constexpr int WT_DPR = 1703936;  // [100][256]
constexpr int WT_TOT = 1729536;

// ---------------- prep: transpose + convert all weights to bf16 B^T -------
struct PrepTab {
  const float* src[9];
  int K[9];
  int N[9];
  int prefix[10];
};

__global__ __launch_bounds__(256) void prep_w(PrepTab t, u16* __restrict__ dst){
  int gid = blockIdx.x * 256 + threadIdx.x;
  if (gid >= t.prefix[9]) return;
  int i = 0;
  while (gid >= t.prefix[i+1]) ++i;
  int e  = gid - t.prefix[i];
  int Ni = t.N[i];
  int k  = e / Ni;
  int n  = e - k * Ni;
  dst[t.prefix[i] + (size_t)n * t.K[i] + k] = f2bf(t.src[i][(size_t)k * Ni + n]);
}

// ---------------- build A = [h_sem | e_struct] bf16 [N,1024] --------------
__global__ __launch_bounds__(256) void build_A(const float* __restrict__ hsem,
                                               const float* __restrict__ est,
                                               u16* __restrict__ out){
  int gid = blockIdx.x * 256 + threadIdx.x;   // one thread per 8 cols
  int row = gid >> 7;
  int c   = (gid & 127) << 3;
  const float* src = (c < 768) ? (hsem + (size_t)row * 768 + c)
                               : (est  + (size_t)row * 256 + (c - 768));
  float4 v0 = *(const float4*)src;
  float4 v1 = *(const float4*)(src + 4);
  uint4 o;
  o.x = (u32)f2bf(v0.x) | ((u32)f2bf(v0.y) << 16);
  o.y = (u32)f2bf(v0.z) | ((u32)f2bf(v0.w) << 16);
  o.z = (u32)f2bf(v1.x) | ((u32)f2bf(v1.y) << 16);
  o.w = (u32)f2bf(v1.z) | ((u32)f2bf(v1.w) << 16);
  *(uint4*)(out + (size_t)row * 1024 + c) = o;
}

// ======== 256x256 / 8-wave / BK=64 4-phase pipelined MFMA GEMM ===========
// C[M,N] = A[M,K]bf16 * B^T[N,K]bf16.  512 threads (2x4 waves, 128x64/wave).
// T3+T4 schedule (the regime-gate prerequisite): per K-tile, 4 phases, each
// {ds_read reg subtile || 2 global_load_lds (stage kt+1) || s_barrier ||
//  lgkmcnt(0)+sched_barrier || setprio(1) 16 MFMA setprio(0)}.
// LDS 128 KB = 2 buf x (A[256][64] + B[256][64]) bf16; stage of kt+1 writes
// buf[~kt&1] (freed by kt-1; WAR closed by tile-top barrier).  A-halves
// (HBM-prone) staged phases 1-2 so they are 2-3 phases old at the next
// tile-top vmcnt(0) (loads mostly landed; B is L2-resident).
// Register audit (launch_bounds(512,2) -> 256 cap): acc 128 + Afrag 32
// (reused across halves) + Bfrag 32 + addr ~25 = ~220.  NO SPILL (r3 lesson:
// watch VGPR_Count; 64 = spilled acc).
// Bank swizzle both-sides (rule 21): LDS(row, slot) holds k-chunk
// slot^(row&7); global source col pre-swizzled; ds_read uses same XOR.
// MODE 0: store bf16 | 3: tanh*ctx row-reduce score partial (per N-tile),
// race-free cross-wave reduce via red[].
template<int MODE, bool BIAS>
__global__ __launch_bounds__(512, 2) void gemm256(
    const u16* __restrict__ A, const u16* __restrict__ B,
    int M, int N, int K,
    const float* __restrict__ bias,
    u16* __restrict__ outb,
    const float* __restrict__ ctx, float* __restrict__ scorep)
{
  __shared__ u16 S[2 * 32768];       // 128 KB: buf p at byte p*65536; B at +32768
  __shared__ float red[8 * 128];     // MODE3 cross-wave reduce scratch (4 KB)
  const int tid = threadIdx.x;
  const int wid = tid >> 6, lane = tid & 63;
  const int lq = lane >> 4, lr = lane & 15;

  // XCD-bijective chunked swizzle + N-fastest tile decode
  const int ny  = N >> 8;
  const int nwg = (int)gridDim.x;
  const int q   = nwg >> 3, r = nwg & 7;
  const int xcd = (int)blockIdx.x & 7, pos = (int)blockIdx.x >> 3;
  const int lid = (xcd < r ? xcd * (q + 1) : r * (q + 1) + (xcd - r) * q) + pos;
  const int ty  = lid % ny, tx = lid / ny;
  const int m0  = tx << 8, n0 = ty << 8;

  const int wr = wid >> 2, wc = wid & 3;      // 2 x 4 wave grid
  const int wrow = wr << 7, wcol = wc << 6;   // 128 x 64 per-wave tile

  // ---- staging addresses: 4 gloads per matrix per K-tile (8 KB each).
  // gload g covers LDS rows [g*64, g*64+64); thread t -> row g*64 + (t>>3),
  // dest slot t&7; source k-chunk = (t&7)^((t>>3)&7)  [= slot^(row&7)].
  const int trow = tid >> 3;                         // 0..63
  const int tcol = (((tid & 7) ^ (trow & 7)) << 3);  // swizzled source col
  int ra0 = min(m0 +       trow, M - 1);
  int ra1 = min(m0 +  64 + trow, M - 1);
  int ra2 = min(m0 + 128 + trow, M - 1);
  int ra3 = min(m0 + 192 + trow, M - 1);
  const u16* pa0 = A + (size_t)ra0 * K + tcol;
  const u16* pa1 = A + (size_t)ra1 * K + tcol;
  const u16* pa2 = A + (size_t)ra2 * K + tcol;
  const u16* pa3 = A + (size_t)ra3 * K + tcol;
  const u16* pb0 = B + (size_t)(n0 +       trow) * K + tcol;
  const u16* pb1 = B + (size_t)(n0 +  64 + trow) * K + tcol;
  const u16* pb2 = B + (size_t)(n0 + 128 + trow) * K + tcol;
  const u16* pb3 = B + (size_t)(n0 + 192 + trow) * K + tcol;

  floatx4 acc[8][4];
  #pragma unroll
  for (int i = 0; i < 8; ++i)
    #pragma unroll
    for (int j = 0; j < 4; ++j)
      acc[i][j] = floatx4{0.f, 0.f, 0.f, 0.f};

  const int NT = K >> 6;            // BK = 64

  // prologue: stage tile 0 into buf 0 (8 gloads)
  {
    char* d = (char*)S + (wid << 10);
    async16(pa0, d);         async16(pa1, d + 8192);
    async16(pa2, d + 16384); async16(pa3, d + 24576);
    async16(pb0, d + 32768); async16(pb1, d + 40960);
    async16(pb2, d + 49152); async16(pb3, d + 57344);
    pa0 += 64; pa1 += 64; pa2 += 64; pa3 += 64;
    pb0 += 64; pb1 += 64; pb2 += 64; pb3 += 64;
  }

  const int rxa = lr & 7;           // read-side XOR (row&7 for frag rows)

  for (int kt = 0; kt < NT; ++kt) {
    // tile kt's 8 loads (issued during kt-1 phases 1-2, 2-4 phases old) must
    // have landed in ALL waves; barrier also closes WAR for kt+1 staging.
    asm volatile("s_waitcnt vmcnt(0)" ::: "memory");
    __builtin_amdgcn_s_barrier();
    __builtin_amdgcn_sched_barrier(0);

    const char* ap = (const char*)S + ((kt & 1) << 16);
    const char* bp = ap + 32768;
    char* sd = (char*)S + (((kt + 1) & 1) << 16) + (wid << 10);
    const bool pf = (kt + 1 < NT);

    short8 af[2][4], b0[2][2], b1[2][2];

    // ---- phase 1: A-frags (mi 0-3) + B-frags (ni 0-1); stage A g0,g1
    #pragma unroll
    for (int kc = 0; kc < 2; ++kc) {
      const int sl = ((((kc << 2) | lq) ^ rxa) << 4);
      #pragma unroll
      for (int mi = 0; mi < 4; ++mi)
        af[kc][mi] = *(const short8*)(ap + ((wrow + mi * 16 + lr) << 7) + sl);
      #pragma unroll
      for (int ni = 0; ni < 2; ++ni)
        b0[kc][ni] = *(const short8*)(bp + ((wcol + ni * 16 + lr) << 7) + sl);
    }
    if (pf) { async16(pa0, sd); async16(pa1, sd + 8192); pa0 += 64; pa1 += 64; }
    __builtin_amdgcn_s_barrier();
    asm volatile("s_waitcnt lgkmcnt(0)" ::: "memory");
    __builtin_amdgcn_sched_barrier(0);
    __builtin_amdgcn_s_setprio(1);
    #pragma unroll
    for (int kc = 0; kc < 2; ++kc)
      #pragma unroll
      for (int mi = 0; mi < 4; ++mi)
        #pragma unroll
        for (int ni = 0; ni < 2; ++ni)
          acc[mi][ni] = __builtin_amdgcn_mfma_f32_16x16x32_bf16(af[kc][mi], b0[kc][ni], acc[mi][ni], 0, 0, 0);
    __builtin_amdgcn_s_setprio(0);

    // ---- phase 2: B-frags (ni 2-3); stage A g2,g3
    #pragma unroll
    for (int kc = 0; kc < 2; ++kc) {
      const int sl = ((((kc << 2) | lq) ^ rxa) << 4);
      #pragma unroll
      for (int ni = 0; ni < 2; ++ni)
        b1[kc][ni] = *(const short8*)(bp + ((wcol + (ni + 2) * 16 + lr) << 7) + sl);
    }
    if (pf) { async16(pa2, sd + 16384); async16(pa3, sd + 24576); pa2 += 64; pa3 += 64; }
    __builtin_amdgcn_s_barrier();
    asm volatile("s_waitcnt lgkmcnt(0)" ::: "memory");
    __builtin_amdgcn_sched_barrier(0);
    __builtin_amdgcn_s_setprio(1);
    #pragma unroll
    for (int kc = 0; kc < 2; ++kc)
      #pragma unroll
      for (int mi = 0; mi < 4; ++mi)
        #pragma unroll
        for (int ni = 0; ni < 2; ++ni)
          acc[mi][ni + 2] = __builtin_amdgcn_mfma_f32_16x16x32_bf16(af[kc][mi], b1[kc][ni], acc[mi][ni + 2], 0, 0, 0);
    __builtin_amdgcn_s_setprio(0);

    // ---- phase 3: A-frags (mi 4-7, reuse af regs); stage B g0,g1
    #pragma unroll
    for (int kc = 0; kc < 2; ++kc) {
      const int sl = ((((kc << 2) | lq) ^ rxa) << 4);
      #pragma unroll
      for (int mi = 0; mi < 4; ++mi)
        af[kc][mi] = *(const short8*)(ap + ((wrow + (mi + 4) * 16 + lr) << 7) + sl);
    }
    if (pf) { async16(pb0, sd + 32768); async16(pb1, sd + 40960); pb0 += 64; pb1 += 64; }
    __builtin_amdgcn_s_barrier();
    asm volatile("s_waitcnt lgkmcnt(0)" ::: "memory");
    __builtin_amdgcn_sched_barrier(0);
    __builtin_amdgcn_s_setprio(1);
    #pragma unroll
    for (int kc = 0; kc < 2; ++kc)
      #pragma unroll
      for (int mi = 0; mi < 4; ++mi)
        #pragma unroll
        for (int ni = 0; ni < 2; ++ni)
          acc[mi + 4][ni] = __builtin_amdgcn_mfma_f32_16x16x32_bf16(af[kc][mi], b0[kc][ni], acc[mi + 4][ni], 0, 0, 0);
    __builtin_amdgcn_s_setprio(0);

    // ---- phase 4: no reads (af, b1 live); stage B g2,g3
    if (pf) { async16(pb2, sd + 49152); async16(pb3, sd + 57344); pb2 += 64; pb3 += 64; }
    __builtin_amdgcn_s_barrier();
    __builtin_amdgcn_sched_barrier(0);
    __builtin_amdgcn_s_setprio(1);
    #pragma unroll
    for (int kc = 0; kc < 2; ++kc)
      #pragma unroll
      for (int mi = 0; mi < 4; ++mi)
        #pragma unroll
        for (int ni = 0; ni < 2; ++ni)
          acc[mi + 4][ni + 2] = __builtin_amdgcn_mfma_f32_16x16x32_bf16(af[kc][mi], b1[kc][ni], acc[mi + 4][ni + 2], 0, 0, 0);
    __builtin_amdgcn_s_setprio(0);
  }

  // C/D layout (r0/r1-proven orientation): for (mi,ni):
  // row gr = m0+wrow+mi*16+lq*4+r2, col gc = n0+wcol+ni*16+lr.
  if constexpr (MODE == 3) {
    #pragma unroll
    for (int mi = 0; mi < 8; ++mi) {
      #pragma unroll
      for (int r2 = 0; r2 < 4; ++r2) {
        float p = 0.f;
        #pragma unroll
        for (int ni = 0; ni < 4; ++ni) {
          int gc = n0 + wcol + ni * 16 + lr;
          p += tanhf(acc[mi][ni][r2] + bias[gc]) * ctx[gc];
        }
        p += __shfl_xor(p, 1); p += __shfl_xor(p, 2);
        p += __shfl_xor(p, 4); p += __shfl_xor(p, 8);
        if (lr == 0) red[wid * 128 + mi * 16 + (lq << 2) + r2] = p;
      }
    }
    __syncthreads();
    if (tid < 256) {                 // cross-wave: sum 4 wc-partials per row
      int wrr = tid >> 7, rr = tid & 127;
      int base = (wrr << 2) * 128 + rr;
      float s4 = red[base] + red[base + 128] + red[base + 256] + red[base + 384];
      int gr = m0 + (wrr << 7) + rr;
      if (gr < M) scorep[(size_t)ty * M + gr] = s4;
    }
  } else {
    #pragma unroll
    for (int mi = 0; mi < 8; ++mi) {
      int grb = m0 + wrow + mi * 16 + (lq << 2);
      #pragma unroll
      for (int ni = 0; ni < 4; ++ni) {
        int gc = n0 + wcol + ni * 16 + lr;
        float bv = BIAS ? bias[gc] : 0.f;
        #pragma unroll
        for (int r2 = 0; r2 < 4; ++r2) {
          int gr = grb + r2;
          if (gr < M) outb[(size_t)gr * N + gc] = f2bf(acc[mi][ni][r2] + bv);
        }
      }
    }
  }
}

// ---------------- MFMA GEMM 128x128 (small head shapes) -------------------
// MODE 0: store bf16 | 1: store f32 | 2: both
template<int MODE, bool BIAS, bool RELU>
__global__ __launch_bounds__(256) void gemm_bt(
    const u16* __restrict__ A, const u16* __restrict__ B,
    int M, int N, int K, int ny,
    const float* __restrict__ bias,
    u16* __restrict__ outb, float* __restrict__ outf,
    int ldc, int nvalid)
{
  __shared__ u16 As[3 * 4096];
  __shared__ u16 Bs[3 * 4096];
  const int tid  = threadIdx.x;
  const int wave = tid >> 6, lane = tid & 63;

  const int nwg = (int)gridDim.x;
  const int q   = nwg >> 3, r = nwg & 7;
  const int xcd = (int)blockIdx.x & 7, pos = (int)blockIdx.x >> 3;
  const int lid = (xcd < r ? xcd * (q + 1) : r * (q + 1) + (xcd - r) * q) + pos;
  const int ty  = lid % ny, tx = lid / ny;
  const int m0  = tx << 7, n0 = ty << 7;

  const int wm = (wave & 1) << 6, wn = (wave >> 1) << 6;
  const int lq = lane >> 4, lr = lane & 15;

  floatx4 acc[4][4];
  #pragma unroll
  for (int i = 0; i < 4; ++i)
    #pragma unroll
    for (int j = 0; j < 4; ++j)
      acc[i][j] = floatx4{0.f, 0.f, 0.f, 0.f};

  int arow = m0 + (wave << 4) + (lane >> 2);
  int ar0 = min(arow, M - 1);
  int ar1 = min(arow + 64, M - 1);
  int brow = n0 + (wave << 4) + (lane >> 2);
  int br0 = min(brow, N - 1);
  int br1 = min(brow + 64, N - 1);
  const int kc = (((lane & 3) ^ ((lane >> 3) & 3)) << 3);
  const u16* ga0 = A + (size_t)ar0 * K + kc;
  const u16* ga1 = A + (size_t)ar1 * K + kc;
  const u16* gb0 = B + (size_t)br0 * K + kc;
  const u16* gb1 = B + (size_t)br1 * K + kc;

  auto STAGE = [&](int buf){
    u16* as = As + (buf << 12);
    u16* bs = Bs + (buf << 12);
    async16(ga0, as + (wave << 9));
    async16(ga1, as + 2048 + (wave << 9));
    async16(gb0, bs + (wave << 9));
    async16(gb1, bs + 2048 + (wave << 9));
    ga0 += 32; ga1 += 32; gb0 += 32; gb1 += 32;
  };

  const int nIt = K >> 5;
  STAGE(0);
  if (nIt > 1) STAGE(1);
  const int rsw = (lr >> 1) & 3;
  int bt = 0;
  for (int it = 0; it < nIt; ++it) {
    if (it + 1 < nIt) asm volatile("s_waitcnt vmcnt(4) lgkmcnt(0)" ::: "memory");
    else              asm volatile("s_waitcnt vmcnt(0) lgkmcnt(0)" ::: "memory");
    __builtin_amdgcn_s_barrier();
    __builtin_amdgcn_sched_barrier(0);
    if (it + 2 < nIt) { int b2 = bt + 2; if (b2 >= 3) b2 -= 3; STAGE(b2); }
    const u16* as = As + (bt << 12);
    const u16* bs = Bs + (bt << 12);
    short8 af[4], bfr[4];
    #pragma unroll
    for (int mi = 0; mi < 4; ++mi)
      af[mi] = *(const short8*)(as + ((wm + mi * 16 + lr) << 5) + ((lq ^ rsw) << 3));
    #pragma unroll
    for (int ni = 0; ni < 4; ++ni)
      bfr[ni] = *(const short8*)(bs + ((wn + ni * 16 + lr) << 5) + ((lq ^ rsw) << 3));
    #pragma unroll
    for (int mi = 0; mi < 4; ++mi)
      #pragma unroll
      for (int ni = 0; ni < 4; ++ni)
        acc[mi][ni] = __builtin_amdgcn_mfma_f32_16x16x32_bf16(af[mi], bfr[ni], acc[mi][ni], 0, 0, 0);
    if (++bt == 3) bt = 0;
  }

  #pragma unroll
  for (int mi = 0; mi < 4; ++mi) {
    int grb = m0 + wm + mi * 16 + lq * 4;
    #pragma unroll
    for (int ni = 0; ni < 4; ++ni) {
      int gc = n0 + wn + ni * 16 + lr;
      if (gc >= nvalid) continue;
      float bv = BIAS ? bias[gc] : 0.f;
      #pragma unroll
      for (int r2 = 0; r2 < 4; ++r2) {
        int gr = grb + r2;
        if (gr >= M) continue;
        float v = acc[mi][ni][r2] + bv;
        if (RELU) v = fmaxf(v, 0.f);
        if (MODE == 0 || MODE == 2) outb[(size_t)gr * ldc + gc] = f2bf(v);
        if (MODE == 1 || MODE == 2) outf[(size_t)gr * ldc + gc] = v;
      }
    }
  }
}

// ---------------- GCN aggregation: 5-tap stencil along position ----------
DEV float dinv_of(int p){
  return rsqrtf((float)(1 + min(p, 2) + min(99 - p, 2)));
}

template<bool RELU, bool DUAL>
__global__ __launch_bounds__(256) void agg_k(const u16* __restrict__ m,
                                             const float* __restrict__ bias,
                                             u16* __restrict__ outb,
                                             float* __restrict__ outf){
  int gid = blockIdx.x * 256 + threadIdx.x;   // 64 threads per row (8 cols ea)
  int row = gid >> 6;
  int c   = (gid & 63) << 3;
  int pos = row % KPF;
  float ds = dinv_of(pos);
  float a0=0,a1=0,a2=0,a3=0,a4=0,a5=0,a6=0,a7=0;
  #pragma unroll
  for (int d = -2; d <= 2; ++d) {
    int p2 = pos + d;
    if (p2 < 0 || p2 >= KPF) continue;
    float w = ds * dinv_of(p2);
    uint4 v = *(const uint4*)(m + (size_t)(row + d) * DH + c);
    a0 += w * blo(v.x); a1 += w * bhi(v.x);
    a2 += w * blo(v.y); a3 += w * bhi(v.y);
    a4 += w * blo(v.z); a5 += w * bhi(v.z);
    a6 += w * blo(v.w); a7 += w * bhi(v.w);
  }
  float o[8] = {a0,a1,a2,a3,a4,a5,a6,a7};
  #pragma unroll
  for (int j = 0; j < 8; ++j) {
    o[j] += bias[c + j];
    if (RELU) o[j] = fmaxf(o[j], 0.f);
  }
  uint4 st;
  st.x = (u32)f2bf(o[0]) | ((u32)f2bf(o[1]) << 16);
  st.y = (u32)f2bf(o[2]) | ((u32)f2bf(o[3]) << 16);
  st.z = (u32)f2bf(o[4]) | ((u32)f2bf(o[5]) << 16);
  st.w = (u32)f2bf(o[6]) | ((u32)f2bf(o[7]) << 16);
  *(uint4*)(outb + (size_t)row * DH + c) = st;
  if (DUAL) {
    float4 f0 = {o[0], o[1], o[2], o[3]};
    float4 f1 = {o[4], o[5], o[6], o[7]};
    *(float4*)(outf + (size_t)row * DH + c)     = f0;
    *(float4*)(outf + (size_t)row * DH + c + 4) = f1;
  }
}

// ---------------- per-file softmax + attention pooling --------------------
__global__ __launch_bounds__(256) void pool_k(const float* __restrict__ sp,
                                              const u16* __restrict__ hblk,
                                              float* __restrict__ alpha_out,
                                              float* __restrict__ hfile_f,
                                              u16* __restrict__ hfile_b){
  int f = blockIdx.x, tid = threadIdx.x;
  __shared__ float sAl[KPF];
  __shared__ float red[8];
  float s = -INFINITY;
  if (tid < KPF) {
    int r = f * KPF + tid;
    s = sp[r] + sp[NN + r];          // 2 N-tile partials (256-wide each)
  }
  float mx = s;
  for (int off = 32; off >= 1; off >>= 1) mx = fmaxf(mx, __shfl_xor(mx, off));
  if ((tid & 63) == 0) red[tid >> 6] = mx;
  __syncthreads();
  mx = fmaxf(fmaxf(red[0], red[1]), fmaxf(red[2], red[3]));
  float ex = (tid < KPF) ? expf(s - mx) : 0.f;
  float sm = ex;
  for (int off = 32; off >= 1; off >>= 1) sm += __shfl_xor(sm, off);
  if ((tid & 63) == 0) red[4 + (tid >> 6)] = sm;
  __syncthreads();
  sm = red[4] + red[5] + red[6] + red[7];
  float al = ex / sm;
  if (tid < KPF) { alpha_out[(size_t)f * KPF + tid] = al; sAl[tid] = al; }
  __syncthreads();
  const u16* base = hblk + (size_t)f * KPF * DH;
  float acc0 = 0.f, acc1 = 0.f;
  for (int i = 0; i < KPF; ++i) {
    float w = sAl[i];
    acc0 += w * bf2f(base[i * DH + tid]);
    acc1 += w * bf2f(base[i * DH + 256 + tid]);
  }
  hfile_f[(size_t)f * DH + tid]       = acc0;
  hfile_f[(size_t)f * DH + 256 + tid] = acc1;
  hfile_b[(size_t)f * DH + tid]       = f2bf(acc0);
  hfile_b[(size_t)f * DH + 256 + tid] = f2bf(acc1);
}

// ---------------- bug logit: h_file @ W_bug + b ---------------------------
__global__ __launch_bounds__(256) void bug_k(const float* __restrict__ hfile,
                                             const float* __restrict__ w,
                                             const float* __restrict__ b,
                                             float* __restrict__ out){
  int row  = blockIdx.x * 4 + (threadIdx.x >> 6);
  int lane = threadIdx.x & 63;
  const float* h = hfile + (size_t)row * DH;
  float s = 0.f;
  #pragma unroll
  for (int j = 0; j < 8; ++j) s += h[lane + j * 64] * w[lane + j * 64];
  for (int off = 32; off >= 1; off >>= 1) s += __shfl_xor(s, off);
  if (lane == 0) out[row] = s + b[0];
}

// ---------------- ortho loss: mean((z_sh^T z_pr)^2) -----------------------
__global__ __launch_bounds__(256) void ortho_k(const float* __restrict__ zsh,
                                               const float* __restrict__ zpr,
                                               float* __restrict__ part){
  int bi = blockIdx.x >> 4, bj = blockIdx.x & 15;
  int ty = threadIdx.x >> 4, tx = threadIdx.x & 15;
  __shared__ float sa[64 * 16], sb[64 * 16];
  float acc = 0.f;
  for (int k0 = 0; k0 < FF; k0 += 64) {
    #pragma unroll
    for (int q = 0; q < 4; ++q) {
      int kk = ty + q * 16;
      int k  = k0 + kk;
      float va = 0.f, vb = 0.f;
      if (k < FF) {
        va = zsh[(size_t)k * 256 + bi * 16 + tx];
        vb = zpr[(size_t)k * 256 + bj * 16 + tx];
      }
      sa[kk * 16 + tx] = va;
      sb[kk * 16 + tx] = vb;
    }
    __syncthreads();
    #pragma unroll 8
    for (int kk = 0; kk < 64; ++kk) acc += sa[kk * 16 + ty] * sb[kk * 16 + tx];
    __syncthreads();
  }
  float ssq = acc * acc;
  for (int off = 32; off >= 1; off >>= 1) ssq += __shfl_xor(ssq, off);
  __shared__ float r[4];
  if ((threadIdx.x & 63) == 0) r[threadIdx.x >> 6] = ssq;
  __syncthreads();
  if (threadIdx.x == 0) part[blockIdx.x] = r[0] + r[1] + r[2] + r[3];
}

__global__ __launch_bounds__(256) void ortho_fin(const float* __restrict__ part,
                                                 float* __restrict__ out){
  int tid = threadIdx.x;
  float s = part[tid];
  for (int off = 32; off >= 1; off >>= 1) s += __shfl_xor(s, off);
  __shared__ float r[4];
  if ((tid & 63) == 0) r[tid >> 6] = s;
  __syncthreads();
  if (tid == 0) out[0] = (r[0] + r[1] + r[2] + r[3]) * (1.0f / 65536.0f);
}

// ==========================================================================
extern "C" void kernel_launch(void* const* d_in, const int* in_sizes, int n_in,
                              void* d_out, int out_size, void* d_ws, size_t ws_size,
                              hipStream_t stream) {
  const float* h_sem    = (const float*)d_in[0];
  const float* e_struct = (const float*)d_in[1];
  const float* W_fusion = (const float*)d_in[2];
  const float* b_fusion = (const float*)d_in[3];
  const float* W_g1     = (const float*)d_in[4];
  const float* b_g1     = (const float*)d_in[5];
  const float* W_g2     = (const float*)d_in[6];
  const float* b_g2     = (const float*)d_in[7];
  const float* W_att    = (const float*)d_in[8];
  const float* b_att    = (const float*)d_in[9];
  const float* context  = (const float*)d_in[10];
  const float* W_sh1    = (const float*)d_in[11];
  const float* b_sh1    = (const float*)d_in[12];
  const float* W_sh2    = (const float*)d_in[13];
  const float* b_sh2    = (const float*)d_in[14];
  const float* W_pr1    = (const float*)d_in[15];
  const float* b_pr1    = (const float*)d_in[16];
  const float* W_pr2    = (const float*)d_in[17];
  const float* b_pr2    = (const float*)d_in[18];
  const float* W_dpr    = (const float*)d_in[19];
  const float* b_dpr    = (const float*)d_in[20];
  const float* W_bug    = (const float*)d_in[21];
  const float* b_bug    = (const float*)d_in[22];

  char*  ws  = (char*)d_ws;
  float* out = (float*)d_out;

  u16*   Abf    = (u16*)(ws + WS_A);
  u16*   h0b    = (u16*)(ws + WS_H0);
  u16*   m1b    = (u16*)(ws + WS_M1);
  u16*   h1b    = (u16*)(ws + WS_H1);
  u16*   m2b    = (u16*)(ws + WS_M2);
  u16*   hblkb  = (u16*)(ws + WS_HBLK);
  float* scorep = (float*)(ws + WS_SCOREP);
  u16*   WT     = (u16*)(ws + WS_WT);
  u16*   hfileb = (u16*)(ws + WS_HFILEB);
  u16*   tshb   = (u16*)(ws + WS_TSH);
  u16*   tprb   = (u16*)(ws + WS_TPR);
  u16*   zprb   = (u16*)(ws + WS_ZPRB);
  float* opart  = (float*)(ws + WS_ORTHOP);

  // 1. weights -> bf16 B^T
  PrepTab t;
  const float* srcs[9] = {W_fusion, W_g1, W_g2, W_att, W_sh1, W_sh2, W_pr1, W_pr2, W_dpr};
  int Ks[9] = {1024, 512, 512, 512, 512, 256, 512, 256, 256};
  int Ns[9] = {512, 512, 512, 512, 256, 256, 256, 256, 100};
  int pre[10] = {WT_FUS, WT_G1, WT_G2, WT_ATT, WT_SH1, WT_SH2, WT_PR1, WT_PR2, WT_DPR, WT_TOT};
  for (int i = 0; i < 9; ++i) { t.src[i] = srcs[i]; t.K[i] = Ks[i]; t.N[i] = Ns[i]; }
  for (int i = 0; i < 10; ++i) t.prefix[i] = pre[i];
  prep_w<<<(WT_TOT + 255) / 256, 256, 0, stream>>>(t, WT);

  // 2. A = [h_sem | e_struct] bf16
  build_A<<<NN * 128 / 256, 256, 0, stream>>>(h_sem, e_struct, Abf);

  // 3. h0 = A @ W_fusion + b  (bf16)  [391 M-tiles x 2 N-tiles]
  gemm256<0, true><<<391 * 2, 512, 0, stream>>>(
      Abf, WT + WT_FUS, NN, 512, 1024, b_fusion, h0b, nullptr, nullptr);

  // 4. m1 = h0 @ W_g1
  gemm256<0, false><<<391 * 2, 512, 0, stream>>>(
      h0b, WT + WT_G1, NN, 512, 512, nullptr, m1b, nullptr, nullptr);

  // 5. h1 = relu(agg(m1) + b_g1)
  agg_k<true, false><<<NN * 64 / 256, 256, 0, stream>>>(m1b, b_g1, h1b, nullptr);

  // 6. m2 = h1 @ W_g2
  gemm256<0, false><<<391 * 2, 512, 0, stream>>>(
      h1b, WT + WT_G2, NN, 512, 512, nullptr, m2b, nullptr, nullptr);

  // 7. h_blk = agg(m2) + b_g2   (fp32 -> d_out, bf16 -> ws)
  agg_k<false, true><<<NN * 64 / 256, 256, 0, stream>>>(m2b, b_g2, hblkb, out + OUT_HBLK);

  // 8. score partials = rowsum(tanh(h_blk@W_att + b_att) * context)
  gemm256<3, true><<<391 * 2, 512, 0, stream>>>(
      hblkb, WT + WT_ATT, NN, 512, 512, b_att, nullptr, context, scorep);

  // 9. per-file softmax + pooling
  pool_k<<<FF, 256, 0, stream>>>(scorep, hblkb, out + OUT_ALPHA, out + OUT_HFILE, hfileb);

  // 10. heads (128^2 kernel; shapes too small for 256^2)
  gemm_bt<0, true, true><<<8 * 2, 256, 0, stream>>>(
      hfileb, WT + WT_SH1, FF, 256, 512, 2, b_sh1, tshb, nullptr, 256, 256);
  gemm_bt<1, true, false><<<8 * 2, 256, 0, stream>>>(
      tshb, WT + WT_SH2, FF, 256, 256, 2, b_sh2, nullptr, out + OUT_ZSH, 256, 256);
  gemm_bt<0, true, true><<<8 * 2, 256, 0, stream>>>(
      hfileb, WT + WT_PR1, FF, 256, 512, 2, b_pr1, tprb, nullptr, 256, 256);
  gemm_bt<2, true, false><<<8 * 2, 256, 0, stream>>>(
      tprb, WT + WT_PR2, FF, 256, 256, 2, b_pr2, zprb, out + OUT_ZPR, 256, 256);
  gemm_bt<1, true, false><<<8 * 1, 256, 0, stream>>>(
      zprb, WT + WT_DPR, FF, 100, 256, 1, b_dpr, nullptr, out + OUT_LOG, 100, 100);

  // 11. bug logit
  bug_k<<<FF / 4, 256, 0, stream>>>(out + OUT_HFILE, W_bug, b_bug, out + OUT_BUG);

  // 12. ortho loss
  ortho_k<<<256, 256, 0, stream>>>(out + OUT_ZSH, out + OUT_ZPR, opart);
  ortho_fin<<<1, 256, 0, stream>>>(opart, out + OUT_LOSS);
}